// Round 9
// baseline (193.163 us; speedup 1.0000x reference)
//
#include <hip/hip_runtime.h>

#define TT 3
#define CCH 32
#define HH 256
#define WW 256
#define KK 7
#define NQ 64
#define QPB 16
#define V1W 76            // y row length (qwi=15 reads dwords 60..75)
#define V1R 14
#define V1N (V1R*V1W)     // 1064 dwords per channel plane
#define V1P 1088          // padded plane stride, multiple of 32 banks & 16B
#define CHC 8             // channels per chunk
#define NCHUNK 2          // 16 channels per half-block

__device__ __forceinline__ int refl(int i, int n) {
    i = i < 0 ? -i : i;
    return i >= n ? 2*(n-1) - i : i;
}

__device__ __forceinline__ void gload_lds(const float* g, float* l) {
    __builtin_amdgcn_global_load_lds(
        (const __attribute__((address_space(1))) unsigned int*)g,
        (__attribute__((address_space(3))) unsigned int*)l, 4, 0, 0);
}

// FMA block for logical row RR (compile-time), consuming y[16] and x[7][8]
#define FMABLOCK(RR)                                                     \
    _Pragma("unroll")                                                    \
    for (int a = 0; a < 4; ++a) {                                        \
        const int pi = (RR) - a;                                         \
        if (pi >= 0 && pi < 7) {                                         \
            _Pragma("unroll")                                            \
            for (int sw = 0; sw < 8; ++sw)                               \
                _Pragma("unroll")                                        \
                for (int j = 0; j < 7; ++j)                              \
                    acc[a][sw] += x[pi][j] * y[sw + j];                  \
        }                                                                \
    }

// One row step: prefetch row RR+1 into N*, compute from C*
#define ROW(RR, C0,C1,C2v,C3v, N0,N1,N2,N3)                              \
    {                                                                    \
        if ((RR) + 1 < 10) {                                             \
            const float4* yp = (const float4*)(ybase + (4*shh + (RR) + 1) * V1W); \
            N0 = yp[0]; N1 = yp[1]; N2 = yp[2]; N3 = yp[3];              \
        }                                                                \
        const float y[16] = {C0.x,C0.y,C0.z,C0.w,  C1.x,C1.y,C1.z,C1.w,  \
                             C2v.x,C2v.y,C2v.z,C2v.w, C3v.x,C3v.y,C3v.z,C3v.w}; \
        FMABLOCK(RR)                                                     \
    }

// ------------- kernel 1: partial dists, 16 channels per block --------------
__global__ __launch_bounds__(256, 4)
void nls_partial(const float* __restrict__ vid0, const float* __restrict__ vid1,
                 float* __restrict__ ws) {
    __shared__ float v1s[CHC * V1P];   // 34816 B -> 4 resident blocks/CU

    const int bx   = blockIdx.x;
    const int half = bx & 1;
    const int b2   = bx >> 1;
    const int t    = b2 >> 8;
    const int rem  = b2 & 255;
    const int qy   = rem >> 2;
    const int q0   = (rem & 3) * QPB;
    const int qh   = qy * 4;
    const int w0   = 4*q0 - 7;

    const int tid   = threadIdx.x;
    const int qwi   = tid & 15;          // bits 0-3: query
    const int c01   = (tid >> 4) & 3;    // bits 4-5: channel low
    const int c2    = (tid >> 6) & 1;    // bit 6: channel high
    const int shh   = tid >> 7;          // bit 7: sh half
    const int clane = c01 + 4*c2;        // channel 0..7 within chunk
    const int qx    = q0 + qwi;

    // v1 staging offsets (channel-independent)
    int off1[5];
#pragma unroll
    for (int k = 0; k < 5; ++k) {
        int idx = tid + 256*k;
        if (idx < V1N) {
            int r = idx / V1W, wi = idx - r*V1W;
            off1[k] = refl(qh + r - 7, HH) * WW + refl(w0 + wi, WW);
        } else off1[k] = 0;
    }

    float acc[4][8];
#pragma unroll
    for (int a = 0; a < 4; ++a)
#pragma unroll
        for (int b = 0; b < 8; ++b) acc[a][b] = 0.f;

    const float* g0t = vid0 + ((size_t)t*CCH + half*16) * (HH*WW);
    const float* g1t = vid1 + ((size_t)t*CCH + half*16) * (HH*WW);

#pragma unroll 1
    for (int s = 0; s < NCHUNK; ++s) {
        __syncthreads();   // previous chunk's LDS reads complete before overwrite
        // ---- async DMA: v1 chunk (8 channels) straight into LDS ----
#pragma unroll
        for (int ch = 0; ch < CHC; ++ch) {
            const float* p1 = g1t + (size_t)(CHC*s + ch) * (HH*WW);
            float* lb = &v1s[ch*V1P + (tid & ~63)];
#pragma unroll
            for (int k = 0; k < 4; ++k)
                gload_lds(p1 + off1[k], lb + 256*k);
            if (tid < V1N - 1024)
                gload_lds(p1 + off1[4], &v1s[ch*V1P + 1024 + (tid & ~63)]);
        }

        // ---- x patch from global (straight-line) ----
        const float* p0 = g0t + (size_t)(CHC*s + clane) * (HH*WW);
        float x[7][8];
#pragma unroll
        for (int i = 0; i < 7; ++i) {
            const float* rowp = p0 + refl(qh + i - 3, HH) * WW;
            float4 B = *(const float4*)(rowp + 4*qx);
            float4 A;
            if (qx > 0) A = *(const float4*)(rowp + 4*qx - 4);
            else        A = make_float4(0.f, B.w, B.z, B.y);   // reflect at w<0
            x[i][0]=A.y; x[i][1]=A.z; x[i][2]=A.w;
            x[i][3]=B.x; x[i][4]=B.y; x[i][5]=B.z; x[i][6]=B.w;
        }
        __syncthreads();   // DMA drained

        // ---- compute with explicit y double-buffer (named registers) ----
        const float* ybase = &v1s[clane*V1P + 4*qwi];
        float4 Ya0, Ya1, Ya2, Ya3, Yb0, Yb1, Yb2, Yb3;
        {
            const float4* yp = (const float4*)(ybase + (4*shh) * V1W);
            Ya0 = yp[0]; Ya1 = yp[1]; Ya2 = yp[2]; Ya3 = yp[3];
        }
        ROW(0, Ya0,Ya1,Ya2,Ya3, Yb0,Yb1,Yb2,Yb3)
        ROW(1, Yb0,Yb1,Yb2,Yb3, Ya0,Ya1,Ya2,Ya3)
        ROW(2, Ya0,Ya1,Ya2,Ya3, Yb0,Yb1,Yb2,Yb3)
        ROW(3, Yb0,Yb1,Yb2,Yb3, Ya0,Ya1,Ya2,Ya3)
        ROW(4, Ya0,Ya1,Ya2,Ya3, Yb0,Yb1,Yb2,Yb3)
        ROW(5, Yb0,Yb1,Yb2,Yb3, Ya0,Ya1,Ya2,Ya3)
        ROW(6, Ya0,Ya1,Ya2,Ya3, Yb0,Yb1,Yb2,Yb3)
        ROW(7, Yb0,Yb1,Yb2,Yb3, Ya0,Ya1,Ya2,Ya3)
        ROW(8, Ya0,Ya1,Ya2,Ya3, Yb0,Yb1,Yb2,Yb3)
        ROW(9, Yb0,Yb1,Yb2,Yb3, Ya0,Ya1,Ya2,Ya3)
    }

    // ---- reduce over c01 (lane bits 4,5) ----
#pragma unroll
    for (int m = 16; m <= 32; m <<= 1)
#pragma unroll
        for (int a = 0; a < 4; ++a)
#pragma unroll
            for (int b = 0; b < 8; ++b)
                acc[a][b] += __shfl_xor(acc[a][b], m, 64);

    __syncthreads();                 // all LDS reads done; overlay dists
    float* dlds = v1s;               // [c2][16 q][64 shifts]
    if (c01 == 0) {
#pragma unroll
        for (int a = 0; a < 4; ++a) {
            float* dp = &dlds[c2*1024 + qwi*64 + (shh*4 + a)*8];
            *(float4*)(dp)     = make_float4(acc[a][0], acc[a][1], acc[a][2], acc[a][3]);
            *(float4*)(dp + 4) = make_float4(acc[a][4], acc[a][5], acc[a][6], acc[a][7]);
        }
    }
    __syncthreads();

    // ---- combine c2 halves, write this block's 1024 partials to ws ----
    {
        float4 A = *(const float4*)&dlds[4*tid];
        float4 B = *(const float4*)&dlds[1024 + 4*tid];
        float4 R = make_float4(A.x+B.x, A.y+B.y, A.z+B.z, A.w+B.w);
        *(float4*)(ws + (size_t)bx*1024 + 4*tid) = R;
    }
}

// ------------- kernel 2: combine halves + top-7 ----------------------------
__global__ __launch_bounds__(256, 4)
void nls_topk(const float* __restrict__ ws, float* __restrict__ out) {
    __shared__ float dlds[QPB * 64];
    const int p   = blockIdx.x;
    const int t   = p >> 8;
    const int rem = p & 255;
    const int qy  = rem >> 2;
    const int q0  = (rem & 3) * QPB;
    const int qh  = qy * 4;
    const int tid = threadIdx.x;

    const float* a = ws + (size_t)p * 2048;
    for (int i = tid; i < 1024; i += 256) dlds[i] = a[i] + a[i + 1024];
    __syncthreads();

    const int q16 = tid >> 4;
    const int l16 = tid & 15;
    const float* d = &dlds[q16 * 64];
    const int j0 = l16 * 4;
    float cv[4];
#pragma unroll
    for (int jj = 0; jj < 4; ++jj) {
        float v = d[j0 + jj];
        if (j0 + jj == 36) v += 1e30f;    // self bias (selection only)
        cv[jj] = v;
    }
    unsigned mask = 0;
    const int qx = q0 + q16;
    const int q  = (t*NQ + qy)*NQ + qx;
    float* od = out + q*KK;
    float* oi = out + (size_t)TT*NQ*NQ*KK + (size_t)q*KK*3;
    for (int k = 0; k < KK; ++k) {
        float best = -3.4e38f; int bi = 1 << 30;
#pragma unroll
        for (int jj = 0; jj < 4; ++jj)
            if (!(mask & (1u << jj)) && cv[jj] > best) { best = cv[jj]; bi = j0 + jj; }
#pragma unroll
        for (int m = 1; m <= 8; m <<= 1) {
            float ob = __shfl_xor(best, m, 64);
            int  obi = __shfl_xor(bi,  m, 64);
            if (ob > best || (ob == best && obi < bi)) { best = ob; bi = obi; }
        }
        if ((bi >> 2) == l16) mask |= 1u << (bi & 3);
        if (l16 == 0) {
            od[k] = d[bi];                 // unbiased value
            int dh = (bi >> 3) - 4;
            int dw = (bi & 7) - 4;
            oi[k*3 + 0] = (float)t;
            oi[k*3 + 1] = (float)refl(qh + dh, HH);
            oi[k*3 + 2] = (float)refl(qx*4 + dw, WW);
        }
    }
}

extern "C" void kernel_launch(void* const* d_in, const int* in_sizes, int n_in,
                              void* d_out, int out_size, void* d_ws, size_t ws_size,
                              hipStream_t stream) {
    (void)in_sizes; (void)n_in; (void)ws_size; (void)out_size;
    const float* vid0 = (const float*)d_in[0];
    const float* vid1 = (const float*)d_in[1];
    float* out = (float*)d_out;
    float* ws  = (float*)d_ws;   // needs 1536*1024*4 = 6.29 MB
    nls_partial<<<dim3(2 * TT * NQ * (NQ / QPB)), dim3(256), 0, stream>>>(vid0, vid1, ws);
    nls_topk<<<dim3(TT * NQ * (NQ / QPB)), dim3(256), 0, stream>>>(ws, out);
}

// Round 10
// 137.497 us; speedup vs baseline: 1.4048x; 1.4048x over previous
//
#include <hip/hip_runtime.h>

#define TT 3
#define CCH 32
#define HH 256
#define WW 256
#define KK 7
#define NQ 64
#define QPB 16
#define V1W 76            // y row length (qwi=15 reads dwords 60..75)
#define V1R 14
#define V1N (V1R*V1W)     // 1064 dwords per channel plane
#define V1P 1088          // padded plane stride, multiple of 32 banks & 16B
#define CHC 8             // channels per chunk
#define NCHUNK 2          // 16 channels per half-block

__device__ __forceinline__ int refl(int i, int n) {
    i = i < 0 ? -i : i;
    return i >= n ? 2*(n-1) - i : i;
}

__device__ __forceinline__ void gload_lds(const float* g, float* l) {
    __builtin_amdgcn_global_load_lds(
        (const __attribute__((address_space(1))) unsigned int*)g,
        (__attribute__((address_space(3))) unsigned int*)l, 4, 0, 0);
}

// FMA block for logical row RR (compile-time), consuming y[16] and x[7][8]
#define FMABLOCK(RR)                                                     \
    _Pragma("unroll")                                                    \
    for (int a = 0; a < 4; ++a) {                                        \
        const int pi = (RR) - a;                                         \
        if (pi >= 0 && pi < 7) {                                         \
            _Pragma("unroll")                                            \
            for (int sw = 0; sw < 8; ++sw)                               \
                _Pragma("unroll")                                        \
                for (int j = 0; j < 7; ++j)                              \
                    acc[a][sw] += x[pi][j] * y[sw + j];                  \
        }                                                                \
    }

// One row step: prefetch row RR+1 into N*, compute from C*
#define ROW(RR, C0,C1,C2v,C3v, N0,N1,N2,N3)                              \
    {                                                                    \
        if ((RR) + 1 < 10) {                                             \
            const float4* yp = (const float4*)(ybase + (4*shh + (RR) + 1) * V1W); \
            N0 = yp[0]; N1 = yp[1]; N2 = yp[2]; N3 = yp[3];              \
        }                                                                \
        const float y[16] = {C0.x,C0.y,C0.z,C0.w,  C1.x,C1.y,C1.z,C1.w,  \
                             C2v.x,C2v.y,C2v.z,C2v.w, C3v.x,C3v.y,C3v.z,C3v.w}; \
        FMABLOCK(RR)                                                     \
    }

// ------------- kernel 1: partial dists, 16 channels per block --------------
// NOTE: no min-waves launch bound — (256,4)/(256,6) provoke the allocator
// into under-allocating VGPRs and spilling to scratch (measured R4/R9:
// WRITE_SIZE 97-193 MB). LDS (34.8 KB) caps residency at 4 blocks/CU anyway.
__global__ __launch_bounds__(256)
void nls_partial(const float* __restrict__ vid0, const float* __restrict__ vid1,
                 float* __restrict__ ws) {
    __shared__ float v1s[CHC * V1P];   // 34816 B -> 4 resident blocks/CU

    const int bx   = blockIdx.x;
    const int half = bx & 1;
    const int b2   = bx >> 1;
    const int t    = b2 >> 8;
    const int rem  = b2 & 255;
    const int qy   = rem >> 2;
    const int q0   = (rem & 3) * QPB;
    const int qh   = qy * 4;
    const int w0   = 4*q0 - 7;

    const int tid   = threadIdx.x;
    const int qwi   = tid & 15;          // bits 0-3: query
    const int c01   = (tid >> 4) & 3;    // bits 4-5: channel low
    const int c2    = (tid >> 6) & 1;    // bit 6: channel high
    const int shh   = tid >> 7;          // bit 7: sh half
    const int clane = c01 + 4*c2;        // channel 0..7 within chunk
    const int qx    = q0 + qwi;

    // v1 staging offsets (channel-independent)
    int off1[5];
#pragma unroll
    for (int k = 0; k < 5; ++k) {
        int idx = tid + 256*k;
        if (idx < V1N) {
            int r = idx / V1W, wi = idx - r*V1W;
            off1[k] = refl(qh + r - 7, HH) * WW + refl(w0 + wi, WW);
        } else off1[k] = 0;
    }

    float acc[4][8];
#pragma unroll
    for (int a = 0; a < 4; ++a)
#pragma unroll
        for (int b = 0; b < 8; ++b) acc[a][b] = 0.f;

    const float* g0t = vid0 + ((size_t)t*CCH + half*16) * (HH*WW);
    const float* g1t = vid1 + ((size_t)t*CCH + half*16) * (HH*WW);

#pragma unroll 1
    for (int s = 0; s < NCHUNK; ++s) {
        __syncthreads();   // previous chunk's LDS reads complete before overwrite
        // ---- async DMA: v1 chunk (8 channels) straight into LDS ----
#pragma unroll
        for (int ch = 0; ch < CHC; ++ch) {
            const float* p1 = g1t + (size_t)(CHC*s + ch) * (HH*WW);
            float* lb = &v1s[ch*V1P + (tid & ~63)];
#pragma unroll
            for (int k = 0; k < 4; ++k)
                gload_lds(p1 + off1[k], lb + 256*k);
            if (tid < V1N - 1024)
                gload_lds(p1 + off1[4], &v1s[ch*V1P + 1024 + (tid & ~63)]);
        }

        // ---- x patch from global (straight-line) ----
        const float* p0 = g0t + (size_t)(CHC*s + clane) * (HH*WW);
        float x[7][8];
#pragma unroll
        for (int i = 0; i < 7; ++i) {
            const float* rowp = p0 + refl(qh + i - 3, HH) * WW;
            float4 B = *(const float4*)(rowp + 4*qx);
            float4 A;
            if (qx > 0) A = *(const float4*)(rowp + 4*qx - 4);
            else        A = make_float4(0.f, B.w, B.z, B.y);   // reflect at w<0
            x[i][0]=A.y; x[i][1]=A.z; x[i][2]=A.w;
            x[i][3]=B.x; x[i][4]=B.y; x[i][5]=B.z; x[i][6]=B.w;
        }
        __syncthreads();   // DMA drained

        // ---- compute with explicit y double-buffer (named registers) ----
        const float* ybase = &v1s[clane*V1P + 4*qwi];
        float4 Ya0, Ya1, Ya2, Ya3, Yb0, Yb1, Yb2, Yb3;
        {
            const float4* yp = (const float4*)(ybase + (4*shh) * V1W);
            Ya0 = yp[0]; Ya1 = yp[1]; Ya2 = yp[2]; Ya3 = yp[3];
        }
        ROW(0, Ya0,Ya1,Ya2,Ya3, Yb0,Yb1,Yb2,Yb3)
        ROW(1, Yb0,Yb1,Yb2,Yb3, Ya0,Ya1,Ya2,Ya3)
        ROW(2, Ya0,Ya1,Ya2,Ya3, Yb0,Yb1,Yb2,Yb3)
        ROW(3, Yb0,Yb1,Yb2,Yb3, Ya0,Ya1,Ya2,Ya3)
        ROW(4, Ya0,Ya1,Ya2,Ya3, Yb0,Yb1,Yb2,Yb3)
        ROW(5, Yb0,Yb1,Yb2,Yb3, Ya0,Ya1,Ya2,Ya3)
        ROW(6, Ya0,Ya1,Ya2,Ya3, Yb0,Yb1,Yb2,Yb3)
        ROW(7, Yb0,Yb1,Yb2,Yb3, Ya0,Ya1,Ya2,Ya3)
        ROW(8, Ya0,Ya1,Ya2,Ya3, Yb0,Yb1,Yb2,Yb3)
        ROW(9, Yb0,Yb1,Yb2,Yb3, Ya0,Ya1,Ya2,Ya3)
    }

    // ---- reduce over c01 (lane bits 4,5) ----
#pragma unroll
    for (int m = 16; m <= 32; m <<= 1)
#pragma unroll
        for (int a = 0; a < 4; ++a)
#pragma unroll
            for (int b = 0; b < 8; ++b)
                acc[a][b] += __shfl_xor(acc[a][b], m, 64);

    __syncthreads();                 // all LDS reads done; overlay dists
    float* dlds = v1s;               // [c2][16 q][64 shifts]
    if (c01 == 0) {
#pragma unroll
        for (int a = 0; a < 4; ++a) {
            float* dp = &dlds[c2*1024 + qwi*64 + (shh*4 + a)*8];
            *(float4*)(dp)     = make_float4(acc[a][0], acc[a][1], acc[a][2], acc[a][3]);
            *(float4*)(dp + 4) = make_float4(acc[a][4], acc[a][5], acc[a][6], acc[a][7]);
        }
    }
    __syncthreads();

    // ---- combine c2 halves, write this block's 1024 partials to ws ----
    {
        float4 A = *(const float4*)&dlds[4*tid];
        float4 B = *(const float4*)&dlds[1024 + 4*tid];
        float4 R = make_float4(A.x+B.x, A.y+B.y, A.z+B.z, A.w+B.w);
        *(float4*)(ws + (size_t)bx*1024 + 4*tid) = R;
    }
}

// ------------- kernel 2: combine halves + top-7 ----------------------------
__global__ __launch_bounds__(256)
void nls_topk(const float* __restrict__ ws, float* __restrict__ out) {
    __shared__ float dlds[QPB * 64];
    const int p   = blockIdx.x;
    const int t   = p >> 8;
    const int rem = p & 255;
    const int qy  = rem >> 2;
    const int q0  = (rem & 3) * QPB;
    const int qh  = qy * 4;
    const int tid = threadIdx.x;

    const float* a = ws + (size_t)p * 2048;
    for (int i = tid; i < 1024; i += 256) dlds[i] = a[i] + a[i + 1024];
    __syncthreads();

    const int q16 = tid >> 4;
    const int l16 = tid & 15;
    const float* d = &dlds[q16 * 64];
    const int j0 = l16 * 4;
    float cv[4];
#pragma unroll
    for (int jj = 0; jj < 4; ++jj) {
        float v = d[j0 + jj];
        if (j0 + jj == 36) v += 1e30f;    // self bias (selection only)
        cv[jj] = v;
    }
    unsigned mask = 0;
    const int qx = q0 + q16;
    const int q  = (t*NQ + qy)*NQ + qx;
    float* od = out + q*KK;
    float* oi = out + (size_t)TT*NQ*NQ*KK + (size_t)q*KK*3;
    for (int k = 0; k < KK; ++k) {
        float best = -3.4e38f; int bi = 1 << 30;
#pragma unroll
        for (int jj = 0; jj < 4; ++jj)
            if (!(mask & (1u << jj)) && cv[jj] > best) { best = cv[jj]; bi = j0 + jj; }
#pragma unroll
        for (int m = 1; m <= 8; m <<= 1) {
            float ob = __shfl_xor(best, m, 64);
            int  obi = __shfl_xor(bi,  m, 64);
            if (ob > best || (ob == best && obi < bi)) { best = ob; bi = obi; }
        }
        if ((bi >> 2) == l16) mask |= 1u << (bi & 3);
        if (l16 == 0) {
            od[k] = d[bi];                 // unbiased value
            int dh = (bi >> 3) - 4;
            int dw = (bi & 7) - 4;
            oi[k*3 + 0] = (float)t;
            oi[k*3 + 1] = (float)refl(qh + dh, HH);
            oi[k*3 + 2] = (float)refl(qx*4 + dw, WW);
        }
    }
}

extern "C" void kernel_launch(void* const* d_in, const int* in_sizes, int n_in,
                              void* d_out, int out_size, void* d_ws, size_t ws_size,
                              hipStream_t stream) {
    (void)in_sizes; (void)n_in; (void)ws_size; (void)out_size;
    const float* vid0 = (const float*)d_in[0];
    const float* vid1 = (const float*)d_in[1];
    float* out = (float*)d_out;
    float* ws  = (float*)d_ws;   // needs 1536*1024*4 = 6.29 MB
    nls_partial<<<dim3(2 * TT * NQ * (NQ / QPB)), dim3(256), 0, stream>>>(vid0, vid1, ws);
    nls_topk<<<dim3(TT * NQ * (NQ / QPB)), dim3(256), 0, stream>>>(ws, out);
}

// Round 11
// 126.055 us; speedup vs baseline: 1.5324x; 1.0908x over previous
//
#include <hip/hip_runtime.h>

#define TT 3
#define CCH 32
#define HH 256
#define WW 256
#define KK 7
#define NQ 64
#define QPB 16
#define V1W 76            // y row length (qwi=15 reads dwords 60..75)
#define V1R 14
#define V1N (V1R*V1W)     // 1064 dwords per channel plane
#define V1P 1088          // padded plane stride (mod 32 == 0, 16B aligned)
#define V0W 72            // x row length
#define V0N (7*V0W)       // 504 dwords per channel plane
#define V0P 512           // padded plane stride (mod 32 == 0, 16B aligned)
#define CHC 8             // channels per chunk
#define NCHUNK 4

__device__ __forceinline__ int refl(int i, int n) {
    i = i < 0 ? -i : i;
    return i >= n ? 2*(n-1) - i : i;
}

__device__ __forceinline__ void gload_lds(const float* g, float* l) {
    __builtin_amdgcn_global_load_lds(
        (const __attribute__((address_space(1))) unsigned int*)g,
        (__attribute__((address_space(3))) unsigned int*)l, 4, 0, 0);
}

// load x row I (8 floats, 2x ds_read_b128) into named regs
#define XL(I, XA, XB) { const float4* xp = (const float4*)(xbase + (I)*V0W); \
                        XA = xp[0]; XB = xp[1]; }
// prefetch y row RR into named regs
#define YPREF(RR, N0,N1,N2,N3) { \
    const float4* yp = (const float4*)(ybase + (4*shh + (RR)) * V1W); \
    N0 = yp[0]; N1 = yp[1]; N2 = yp[2]; N3 = yp[3]; }
// y register matrix from 4 float4s
#define YMAT(C0,C1,C2,C3) const float y[16] = { \
    C0.x,C0.y,C0.z,C0.w, C1.x,C1.y,C1.z,C1.w, \
    C2.x,C2.y,C2.z,C2.w, C3.x,C3.y,C3.z,C3.w };
// one 56-FMA block: acc row AIDX += x(XA,XB) correlated with y window
#define FMAROW(AIDX, XA, XB) { \
    _Pragma("unroll") for (int sw = 0; sw < 8; ++sw) { \
        acc[AIDX][sw] += XA.x*y[sw+0]; acc[AIDX][sw] += XA.y*y[sw+1]; \
        acc[AIDX][sw] += XA.z*y[sw+2]; acc[AIDX][sw] += XA.w*y[sw+3]; \
        acc[AIDX][sw] += XB.x*y[sw+4]; acc[AIDX][sw] += XB.y*y[sw+5]; \
        acc[AIDX][sw] += XB.z*y[sw+6]; } }

__global__ __launch_bounds__(256)
void nls_kernel(const float* __restrict__ vid0, const float* __restrict__ vid1,
                float* __restrict__ out) {
    __shared__ float v1s[CHC * V1P];   // 34816 B
    __shared__ float v0s[CHC * V0P];   // 16384 B -> 51200 total, 3 blocks/CU

    const int bx  = blockIdx.x;
    const int t   = bx >> 8;
    const int rem = bx & 255;
    const int qy  = rem >> 2;
    const int q0  = (rem & 3) * QPB;
    const int qh  = qy * 4;
    const int w0  = 4*q0 - 7;

    const int tid   = threadIdx.x;
    const int qwi   = tid & 15;          // bits 0-3: query
    const int c01   = (tid >> 4) & 3;    // bits 4-5: channel low
    const int c2    = (tid >> 6) & 1;    // bit 6: channel high
    const int shh   = tid >> 7;          // bit 7: sh half
    const int clane = c01 + 4*c2;        // channel 0..7 within chunk

    // staging offsets (channel-independent, pre-reflected)
    int off1[5];
#pragma unroll
    for (int k = 0; k < 5; ++k) {
        int idx = tid + 256*k;
        if (idx < V1N) {
            int r = idx / V1W, wi = idx - r*V1W;
            off1[k] = refl(qh + r - 7, HH) * WW + refl(w0 + wi, WW);
        } else off1[k] = 0;
    }
    int off0[2];
#pragma unroll
    for (int k = 0; k < 2; ++k) {
        int idx = tid + 256*k;
        if (idx < V0N) {
            int r = idx / V0W, wi = idx - r*V0W;
            off0[k] = refl(qh + r - 3, HH) * WW + refl(w0 + wi, WW);
        } else off0[k] = 0;
    }

    float acc[4][8];
#pragma unroll
    for (int a = 0; a < 4; ++a)
#pragma unroll
        for (int b = 0; b < 8; ++b) acc[a][b] = 0.f;

    const float* g0t = vid0 + (size_t)t * (CCH*HH*WW);
    const float* g1t = vid1 + (size_t)t * (CCH*HH*WW);

#pragma unroll 1
    for (int s = 0; s < NCHUNK; ++s) {
        __syncthreads();   // previous chunk's LDS reads complete before overwrite
        // ---- async DMA: v1 + v0 chunk (8 channels) straight into LDS ----
#pragma unroll
        for (int ch = 0; ch < CHC; ++ch) {
            const float* p1 = g1t + (size_t)(CHC*s + ch) * (HH*WW);
            float* lb = &v1s[ch*V1P + (tid & ~63)];
#pragma unroll
            for (int k = 0; k < 4; ++k)
                gload_lds(p1 + off1[k], lb + 256*k);
            if (tid < V1N - 1024)
                gload_lds(p1 + off1[4], &v1s[ch*V1P + 1024 + (tid & ~63)]);
        }
#pragma unroll
        for (int ch = 0; ch < CHC; ++ch) {
            const float* p0 = g0t + (size_t)(CHC*s + ch) * (HH*WW);
            float* lb0 = &v0s[ch*V0P + (tid & ~63)];
            gload_lds(p0 + off0[0], lb0);
            if (tid < V0N - 256)
                gload_lds(p0 + off0[1], lb0 + 256);
        }
        __syncthreads();   // DMA drained

        // ---- compute: x rows from LDS (rolling SSA window), y ping-pong ----
        const float* xbase = &v0s[clane*V0P + 4*qwi + 4];
        const float* ybase = &v1s[clane*V1P + 4*qwi];
        float4 X0a,X0b,X1a,X1b,X2a,X2b,X3a,X3b,X4a,X4b,X5a,X5b,X6a,X6b;
        float4 Ya0,Ya1,Ya2,Ya3, Yb0,Yb1,Yb2,Yb3;
        XL(0, X0a,X0b)
        YPREF(0, Ya0,Ya1,Ya2,Ya3)
        { YPREF(1, Yb0,Yb1,Yb2,Yb3) XL(1, X1a,X1b) YMAT(Ya0,Ya1,Ya2,Ya3)
          FMAROW(0, X0a,X0b) }
        { YPREF(2, Ya0,Ya1,Ya2,Ya3) XL(2, X2a,X2b) YMAT(Yb0,Yb1,Yb2,Yb3)
          FMAROW(0, X1a,X1b) FMAROW(1, X0a,X0b) }
        { YPREF(3, Yb0,Yb1,Yb2,Yb3) XL(3, X3a,X3b) YMAT(Ya0,Ya1,Ya2,Ya3)
          FMAROW(0, X2a,X2b) FMAROW(1, X1a,X1b) FMAROW(2, X0a,X0b) }
        { YPREF(4, Ya0,Ya1,Ya2,Ya3) XL(4, X4a,X4b) YMAT(Yb0,Yb1,Yb2,Yb3)
          FMAROW(0, X3a,X3b) FMAROW(1, X2a,X2b) FMAROW(2, X1a,X1b) FMAROW(3, X0a,X0b) }
        { YPREF(5, Yb0,Yb1,Yb2,Yb3) XL(5, X5a,X5b) YMAT(Ya0,Ya1,Ya2,Ya3)
          FMAROW(0, X4a,X4b) FMAROW(1, X3a,X3b) FMAROW(2, X2a,X2b) FMAROW(3, X1a,X1b) }
        { YPREF(6, Ya0,Ya1,Ya2,Ya3) XL(6, X6a,X6b) YMAT(Yb0,Yb1,Yb2,Yb3)
          FMAROW(0, X5a,X5b) FMAROW(1, X4a,X4b) FMAROW(2, X3a,X3b) FMAROW(3, X2a,X2b) }
        { YPREF(7, Yb0,Yb1,Yb2,Yb3) YMAT(Ya0,Ya1,Ya2,Ya3)
          FMAROW(0, X6a,X6b) FMAROW(1, X5a,X5b) FMAROW(2, X4a,X4b) FMAROW(3, X3a,X3b) }
        { YPREF(8, Ya0,Ya1,Ya2,Ya3) YMAT(Yb0,Yb1,Yb2,Yb3)
          FMAROW(1, X6a,X6b) FMAROW(2, X5a,X5b) FMAROW(3, X4a,X4b) }
        { YPREF(9, Yb0,Yb1,Yb2,Yb3) YMAT(Ya0,Ya1,Ya2,Ya3)
          FMAROW(2, X6a,X6b) FMAROW(3, X5a,X5b) }
        { YMAT(Yb0,Yb1,Yb2,Yb3)
          FMAROW(3, X6a,X6b) }
    }

    // ---- reduce over c01 (lane bits 4,5) ----
#pragma unroll
    for (int m = 16; m <= 32; m <<= 1)
#pragma unroll
        for (int a = 0; a < 4; ++a)
#pragma unroll
            for (int b = 0; b < 8; ++b)
                acc[a][b] += __shfl_xor(acc[a][b], m, 64);

    __syncthreads();                 // all LDS reads done; overlay dists
    float* dlds = v1s;               // [c2][16 q][64 shifts]
    if (c01 == 0) {
#pragma unroll
        for (int a = 0; a < 4; ++a) {
            float* dp = &dlds[c2*1024 + qwi*64 + (shh*4 + a)*8];
            *(float4*)(dp)     = make_float4(acc[a][0], acc[a][1], acc[a][2], acc[a][3]);
            *(float4*)(dp + 4) = make_float4(acc[a][4], acc[a][5], acc[a][6], acc[a][7]);
        }
    }
    __syncthreads();

    // ---- top-7: 16 threads per query ----
    {
        const int q16 = tid >> 4;
        const int l16 = tid & 15;
        const float* d0 = &dlds[q16 * 64];
        const float* d1 = d0 + 1024;
        const int j0 = l16 * 4;
        float cv[4];
#pragma unroll
        for (int jj = 0; jj < 4; ++jj) {
            float v = d0[j0 + jj] + d1[j0 + jj];
            if (j0 + jj == 36) v += 1e30f;    // self bias (selection only)
            cv[jj] = v;
        }
        unsigned mask = 0;
        const int qxx = q0 + q16;
        const int q   = (t*NQ + qy)*NQ + qxx;
        float* od = out + q*KK;
        float* oi = out + (size_t)TT*NQ*NQ*KK + (size_t)q*KK*3;
        for (int k = 0; k < KK; ++k) {
            float best = -3.4e38f; int bi = 1 << 30;
#pragma unroll
            for (int jj = 0; jj < 4; ++jj)
                if (!(mask & (1u << jj)) && cv[jj] > best) { best = cv[jj]; bi = j0 + jj; }
#pragma unroll
            for (int m = 1; m <= 8; m <<= 1) {
                float ob = __shfl_xor(best, m, 64);
                int  obi = __shfl_xor(bi,  m, 64);
                if (ob > best || (ob == best && obi < bi)) { best = ob; bi = obi; }
            }
            if ((bi >> 2) == l16) mask |= 1u << (bi & 3);
            if (l16 == 0) {
                od[k] = d0[bi] + d1[bi];       // unbiased value
                int dh = (bi >> 3) - 4;
                int dw = (bi & 7) - 4;
                oi[k*3 + 0] = (float)t;
                oi[k*3 + 1] = (float)refl(qh + dh, HH);
                oi[k*3 + 2] = (float)refl(qxx*4 + dw, WW);
            }
        }
    }
}

extern "C" void kernel_launch(void* const* d_in, const int* in_sizes, int n_in,
                              void* d_out, int out_size, void* d_ws, size_t ws_size,
                              hipStream_t stream) {
    (void)in_sizes; (void)n_in; (void)d_ws; (void)ws_size; (void)out_size;
    const float* vid0 = (const float*)d_in[0];
    const float* vid1 = (const float*)d_in[1];
    float* out = (float*)d_out;
    nls_kernel<<<dim3(TT * NQ * (NQ / QPB)), dim3(256), 0, stream>>>(vid0, vid1, out);
}